// Round 3
// baseline (90.465 us; speedup 1.0000x reference)
//
#include <hip/hip_runtime.h>

// Banded-block sparse attention, B=4, S=4096, D=128, block=64, w=32.
// Masked scores are 0 (not -inf) -> closed-form out-of-band correction.
// fp16 MFMA path, exp2 domain, swapped QK^T, defer-max (THR=8 log2 units).
//
// R3: fully independent waves, ZERO LDS / ZERO barriers in attn.
//  - K/V/Q pre-packed into per-lane MFMA fragment order (1KB coalesced loads,
//    L2-resident: ~3MB working set per XCD).
//  - V fragments pre-permuted with pi(ks2,lg,e)=ks2*32+(e>>2)*16+lg*4+(e&3)
//    so the PV A-operand is each lane's OWN sacc values (contraction-index
//    relabeling): P never leaves registers. No LDS roundtrip, no bpermute.
//  - wave = (b, ib, qh, ck): 32 q-rows, 1/8 of ib's band. 4096 waves.
//  - launch_bounds(256,3): target <=170 combined VGPR+AGPR -> 3 waves/SIMD.

typedef _Float16 f16;
typedef __attribute__((ext_vector_type(8))) _Float16 f16x8;
typedef __attribute__((ext_vector_type(4))) _Float16 f16x4;
typedef __attribute__((ext_vector_type(4))) float f32x4;

#define MFMA16(a, b, c) __builtin_amdgcn_mfma_f32_16x16x32_f16((a), (b), (c), 0, 0, 0)

#define BATCH 4
#define SEQ   4096
#define DIM   128
#define NB    64
#define WBAND 32
#define LOG2E 1.44269504088896f
#define DTHR  8.0f
#define TSTR  72

#define TILE  16384   // one K or V tile in fragment order: 16 frags x 64 lanes x 16B
#define QTILE 8192    // one qh Q-tile: 8 frags x 64 lanes x 16B
#define CHUNKS 8
#define PART_STRIDE 16896  // 16KB o (f16 [2 qh][8 slot][64 lane][16B]) + 512B (m,l)

// ---------------------------------------------------------------------------
// Packs K, V, Q into MFMA fragment order (f16), plus V column sums BS.
// KF frag(ks,jt), lane l: K[s0 + jt*16 + (l&15)][ks*32 + (l>>4)*8 + e]
// VF frag(ks2,nt), lane l: V[s0 + pi(ks2,lg,e)][nt*16 + (l&15)]
// QF qh, frag(s,ks), lane l: Q[s0 + qh*32 + s*16 + (l&15)][ks*32+(l>>4)*8+e]*LOG2E
__global__ __launch_bounds__(256) void convert_kernel(
    const float* __restrict__ Q, const float* __restrict__ K,
    const float* __restrict__ V, f16* __restrict__ KF, f16* __restrict__ VF,
    f16* __restrict__ QF, float* __restrict__ BS) {
  __shared__ f16 T[128 * TSTR];
  const int blk = blockIdx.x;
  const int b = blk >> 6, jb = blk & 63;
  const int s0 = jb * 64;
  const int t = threadIdx.x;

  // V -> T (d-major transpose, f16)
#pragma unroll
  for (int i = 0; i < 8; ++i) {
    int idx = t + i * 256;
    int row = idx >> 5;
    int c4 = (idx & 31) * 4;
    float4 v = *(const float4*)(V + (size_t)(b * SEQ + s0 + row) * DIM + c4);
    T[(c4 + 0) * TSTR + row] = (f16)v.x;
    T[(c4 + 1) * TSTR + row] = (f16)v.y;
    T[(c4 + 2) * TSTR + row] = (f16)v.z;
    T[(c4 + 3) * TSTR + row] = (f16)v.w;
  }

  // KF fragments (no LDS needed)
  char* kt = (char*)KF + (size_t)blk * TILE;
#pragma unroll
  for (int i = 0; i < 4; ++i) {
    int idx = t + i * 256;           // frag*64 + lane
    int frag = idx >> 6, lane = idx & 63;
    int ks = frag >> 2, jt = frag & 3;
    int row = jt * 16 + (lane & 15);
    int d0 = ks * 32 + (lane >> 4) * 8;
    const float* src = K + ((size_t)(b * SEQ + s0 + row)) * DIM + d0;
    float4 a = *(const float4*)src;
    float4 d = *(const float4*)(src + 4);
    f16x8 h = {(f16)a.x, (f16)a.y, (f16)a.z, (f16)a.w,
               (f16)d.x, (f16)d.y, (f16)d.z, (f16)d.w};
    *(f16x8*)(kt + idx * 16) = h;
  }

  // QF fragments (pre-scaled by log2 e)
  char* qt = (char*)QF + (size_t)blk * (2 * QTILE);
#pragma unroll
  for (int i = 0; i < 4; ++i) {
    int idx = t + i * 256;           // qh*512 + frag*64 + lane
    int qh = idx >> 9, frag = (idx >> 6) & 7, lane = idx & 63;
    int s = frag >> 2, ks = frag & 3;
    int row = qh * 32 + s * 16 + (lane & 15);
    int d0 = ks * 32 + (lane >> 4) * 8;
    const float* src = Q + ((size_t)(b * SEQ + s0 + row)) * DIM + d0;
    float4 a = *(const float4*)src;
    float4 d = *(const float4*)(src + 4);
    f16x8 h = {(f16)(a.x * LOG2E), (f16)(a.y * LOG2E), (f16)(a.z * LOG2E),
               (f16)(a.w * LOG2E), (f16)(d.x * LOG2E), (f16)(d.y * LOG2E),
               (f16)(d.z * LOG2E), (f16)(d.w * LOG2E)};
    *(f16x8*)(qt + idx * 16) = h;
  }
  __syncthreads();

  // VF fragments with pi row-permutation, gathered from T
  char* vt = (char*)VF + (size_t)blk * TILE;
#pragma unroll
  for (int i = 0; i < 4; ++i) {
    int idx = t + i * 256;
    int frag = idx >> 6, lane = idx & 63;
    int ks2 = frag >> 3, nt = frag & 7;
    int d = nt * 16 + (lane & 15);
    int k0 = ks2 * 32 + ((lane >> 4) & 3) * 4;
    f16x4 x = *(const f16x4*)(T + d * TSTR + k0);
    f16x4 y = *(const f16x4*)(T + d * TSTR + k0 + 16);
    f16x8 h = {x[0], x[1], x[2], x[3], y[0], y[1], y[2], y[3]};
    *(f16x8*)(vt + idx * 16) = h;
  }

  if (t < 128) {
    float s = 0.f;
    for (int k = 0; k < 64; ++k) s += (float)T[t * TSTR + k];
    BS[(b * NB + jb) * DIM + t] = s;
  }
}

// ---------------------------------------------------------------------------
// Independent-wave attention: no LDS, no __syncthreads.
__global__ __launch_bounds__(256, 3) void attn_kernel(
    const f16* __restrict__ KF, const f16* __restrict__ VF,
    const f16* __restrict__ QF, char* __restrict__ PART) {
  const int id = blockIdx.x;
  const int t = threadIdx.x;
  const int w = t >> 6, l = t & 63, lg = l >> 4, ll = l & 15;

  // XCD-contiguous (b, ib): each XCD works one b, 32 contiguous ib (~3MB L2 set)
  const int lin = (id & 7) * 128 + (id >> 3);  // 0..1023
  const int b = lin >> 8;
  const int ib = (lin >> 2) & 63;
  const int ckp = lin & 3;
  const int ck = ckp * 2 + (w >> 1);  // waves 0,1 share ck (and K/V tiles -> L1)
  const int qh = w & 1;

  const int jlo = max(0, ib - WBAND);
  const int jhi = min(NB, ib + WBAND);
  const int n = jhi - jlo;            // 32..64
  const int c = (n + 7) >> 3;         // 4..8
  const int j0 = jlo + ck * c;
  const int nloc = min(c, jhi - j0);  // <=0 -> empty chunk (zero partial)

  // Q fragments, resident (pre-scaled f16)
  const char* qt = (const char*)QF +
                   ((size_t)((b * NB + ib) * 2 + qh)) * QTILE + (size_t)l * 16;
  f16x8 qf[2][4];
#pragma unroll
  for (int s = 0; s < 2; ++s)
#pragma unroll
    for (int ks = 0; ks < 4; ++ks)
      qf[s][ks] = *(const f16x8*)(qt + (s * 4 + ks) * 1024);

  float m2[2] = {0.f, 0.f};   // running max (log2 domain); 0 = masked baseline
  float ell[2] = {0.f, 0.f};  // per-lane partial row sums
  f32x4 o[2][8];
#pragma unroll
  for (int s = 0; s < 2; ++s)
#pragma unroll
    for (int nt = 0; nt < 8; ++nt) o[s][nt] = (f32x4){0.f, 0.f, 0.f, 0.f};

  const char* kt = (const char*)KF + ((size_t)(b * NB + j0)) * TILE + (size_t)l * 16;
  const char* vt = (const char*)VF + ((size_t)(b * NB + j0)) * TILE + (size_t)l * 16;

  for (int tt = 0; tt < nloc; ++tt) {
    // ---- QK^T (swapped): sacc[s][jt][r] = S[q = s*16-block col ll][k = jt*16+lg*4+r]
    f32x4 sacc[2][4];
#pragma unroll
    for (int s = 0; s < 2; ++s)
#pragma unroll
      for (int jt = 0; jt < 4; ++jt) sacc[s][jt] = (f32x4){0.f, 0.f, 0.f, 0.f};

    __builtin_amdgcn_s_setprio(1);
#pragma unroll
    for (int ks = 0; ks < 4; ++ks) {
#pragma unroll
      for (int jt = 0; jt < 4; ++jt) {
        f16x8 kf = *(const f16x8*)(kt + (ks * 4 + jt) * 1024);
        sacc[0][jt] = MFMA16(kf, qf[0][ks], sacc[0][jt]);
        sacc[1][jt] = MFMA16(kf, qf[1][ks], sacc[1][jt]);
      }
    }
    __builtin_amdgcn_s_setprio(0);

    // ---- softmax, fully in-register; pa = lane's own p values (pi-permuted V)
    f16x8 pa[2][2];
#pragma unroll
    for (int s = 0; s < 2; ++s) {
      float vm = sacc[s][0][0];
#pragma unroll
      for (int jt = 0; jt < 4; ++jt)
#pragma unroll
        for (int r = 0; r < 4; ++r) vm = fmaxf(vm, sacc[s][jt][r]);
      vm = fmaxf(vm, __shfl_xor(vm, 16));
      vm = fmaxf(vm, __shfl_xor(vm, 32));

      if (__any(vm - m2[s] > DTHR)) {
        float nm = fmaxf(m2[s], vm);
        float scl = __builtin_amdgcn_exp2f(m2[s] - nm);
        m2[s] = nm;
        ell[s] *= scl;
        float sb[4];
#pragma unroll
        for (int r = 0; r < 4; ++r) sb[r] = __shfl(scl, lg * 4 + r);
#pragma unroll
        for (int nt = 0; nt < 8; ++nt)
#pragma unroll
          for (int r = 0; r < 4; ++r) o[s][nt][r] *= sb[r];
      }

      float rsum = 0.f;
#pragma unroll
      for (int ks2 = 0; ks2 < 2; ++ks2) {
        f16x8 pv;
#pragma unroll
        for (int u = 0; u < 2; ++u) {
#pragma unroll
          for (int r = 0; r < 4; ++r) {
            float p = __builtin_amdgcn_exp2f(sacc[s][ks2 * 2 + u][r] - m2[s]);
            rsum += p;
            pv[u * 4 + r] = (f16)p;
          }
        }
        pa[s][ks2] = pv;
      }
      ell[s] += rsum;
    }

    // ---- PV: B = pi-permuted V fragments (direct from L2)
    __builtin_amdgcn_s_setprio(1);
#pragma unroll
    for (int ks2 = 0; ks2 < 2; ++ks2) {
#pragma unroll
      for (int nt = 0; nt < 8; ++nt) {
        f16x8 vbf = *(const f16x8*)(vt + (ks2 * 8 + nt) * 1024);
        o[0][nt] = MFMA16(pa[0][ks2], vbf, o[0][nt]);
        o[1][nt] = MFMA16(pa[1][ks2], vbf, o[1][nt]);
      }
    }
    __builtin_amdgcn_s_setprio(0);

    kt += TILE;
    vt += TILE;
  }

  // finalize per-row sums across lg lanes
#pragma unroll
  for (int s = 0; s < 2; ++s) {
    ell[s] += __shfl_xor(ell[s], 16);
    ell[s] += __shfl_xor(ell[s], 32);
  }

  // partial store (same layout as merge expects): [qh][slot=s*4+g][lane][16B]
  const int pair = b * 32 + (ib >> 1);
  const int half = ib & 1;
  char* pb = PART + ((size_t)((pair * CHUNKS + ck) * 2 + half)) * PART_STRIDE;
#pragma unroll
  for (int s = 0; s < 2; ++s)
#pragma unroll
    for (int g = 0; g < 4; ++g) {
      f16x8 hh;
#pragma unroll
      for (int r = 0; r < 4; ++r) {
        hh[r] = (f16)o[s][2 * g][r];
        hh[4 + r] = (f16)o[s][2 * g + 1][r];
      }
      *(f16x8*)(pb + qh * 8192 + ((s * 4 + g) * 64 + l) * 16) = hh;
    }
  if (lg == 0) {
#pragma unroll
    for (int s = 0; s < 2; ++s)
      *(float2*)(pb + 16384 + (qh * 32 + s * 16 + ll) * 8) =
          make_float2(m2[s], ell[s]);
  }
}

// ---------------------------------------------------------------------------
// Flash-merge of 8 chunk partials + closed-form out-of-band correction.
__global__ __launch_bounds__(256) void merge_kernel(
    const char* __restrict__ PART, const float* __restrict__ BS,
    float* __restrict__ Out) {
  __shared__ float VoutS[DIM];
  __shared__ float mlS[CHUNKS][64][2];

  const int id = blockIdx.x;
  const int lin = (id & 7) * 32 + (id >> 3);  // match attn pair->XCD mapping
  const int pair = lin >> 1, half = lin & 1;
  const int b = pair >> 5;
  const int ib = (pair & 31) * 2 + half;
  const int t = threadIdx.x;
  const int l = t & 63, lg = (t >> 4) & 3, ll = t & 15;
  const int sub = (t >> 6) & 1, qh = t >> 7;

  const int jlo = max(0, ib - WBAND);
  const int jhi = min(NB, ib + WBAND);
  const float cnt_out = (float)(SEQ - (jhi - jlo) * 64);

  if (t < DIM) {
    float s = 0.f;
    for (int j = 0; j < jlo; ++j) s += BS[(b * NB + j) * DIM + t];
    for (int j = jhi; j < NB; ++j) s += BS[(b * NB + j) * DIM + t];
    VoutS[t] = s;
  }

  const size_t pb0 = ((size_t)(pair * CHUNKS * 2 + half)) * PART_STRIDE;
  for (int i = t; i < CHUNKS * 64; i += 256) {
    int k = i >> 6, row = i & 63;
    *(float2*)&mlS[k][row][0] = *(const float2*)(
        PART + pb0 + (size_t)k * 2 * PART_STRIDE + 16384 + row * 8);
  }
  __syncthreads();

  float aw[4][CHUNKS], en[4], inv[4];
#pragma unroll
  for (int r = 0; r < 4; ++r) {
    int row = qh * 32 + sub * 16 + lg * 4 + r;
    float M = mlS[0][row][0];
#pragma unroll
    for (int k = 1; k < CHUNKS; ++k) M = fmaxf(M, mlS[k][row][0]);
    en[r] = __builtin_amdgcn_exp2f(-M);
    float den = cnt_out * en[r];
#pragma unroll
    for (int k = 0; k < CHUNKS; ++k) {
      aw[r][k] = __builtin_amdgcn_exp2f(mlS[k][row][0] - M);
      den += aw[r][k] * mlS[k][row][1];
    }
    inv[r] = 1.f / den;
  }

  float acc[8][4];
#pragma unroll
  for (int nt = 0; nt < 8; ++nt)
#pragma unroll
    for (int r = 0; r < 4; ++r) acc[nt][r] = 0.f;

  for (int k = 0; k < CHUNKS; ++k) {
    const char* oc = PART + pb0 + (size_t)k * 2 * PART_STRIDE + qh * 8192;
#pragma unroll
    for (int g = 0; g < 4; ++g) {
      f16x8 h = *(const f16x8*)(oc + ((sub * 4 + g) * 64 + l) * 16);
#pragma unroll
      for (int r = 0; r < 4; ++r) {
        acc[2 * g][r] += aw[r][k] * (float)h[r];
        acc[2 * g + 1][r] += aw[r][k] * (float)h[4 + r];
      }
    }
  }

  const int q0 = ib * 64;
#pragma unroll
  for (int nt = 0; nt < 8; ++nt) {
    int col = nt * 16 + ll;
    float vout = VoutS[col];
#pragma unroll
    for (int r = 0; r < 4; ++r) {
      int row = qh * 32 + sub * 16 + lg * 4 + r;
      Out[((size_t)(b * SEQ + q0 + row)) * DIM + col] =
          (acc[nt][r] + en[r] * vout) * inv[r];
    }
  }
}

// ---------------------------------------------------------------------------
extern "C" void kernel_launch(void* const* d_in, const int* in_sizes, int n_in,
                              void* d_out, int out_size, void* d_ws, size_t ws_size,
                              hipStream_t stream) {
  const float* Q = (const float*)d_in[0];
  const float* K = (const float*)d_in[1];
  const float* V = (const float*)d_in[2];
  float* Out = (float*)d_out;

  char* ws = (char*)d_ws;
  f16* KF = (f16*)ws;                                   // 4 MB
  f16* VF = (f16*)(ws + (size_t)BATCH * NB * TILE);     // 4 MB
  f16* QF = (f16*)(ws + 2 * (size_t)BATCH * NB * TILE); // 4 MB
  float* BS = (float*)(ws + 3 * (size_t)BATCH * NB * TILE);  // 128 KB
  char* PART = ws + 3 * (size_t)BATCH * NB * TILE + (size_t)BATCH * NB * DIM * 4;

  convert_kernel<<<dim3(BATCH * NB), 256, 0, stream>>>(Q, K, V, KF, VF, QF, BS);
  attn_kernel<<<dim3(BATCH * NB / 2 * CHUNKS), 256, 0, stream>>>(KF, VF, QF, PART);
  merge_kernel<<<dim3(BATCH * NB), 256, 0, stream>>>(PART, BS, Out);
}

// Round 4
// 66.224 us; speedup vs baseline: 1.3660x; 1.3660x over previous
//
#include <hip/hip_runtime.h>

// Banded-block sparse attention, B=4, S=4096, D=128, block=64, w=32.
// Masked scores are 0 (not -inf) -> closed-form out-of-band correction.
// fp16 MFMA path, exp2 domain, swapped QK^T, defer-max (THR=8 log2 units).
//
// R4: R2's pair-wg LDS staging + R3's fragment-order tiles & pi-permuted V
// (P stays in registers; no P-LDS, no XOR swizzle, zero LDS addr math) +
// counted-vmcnt double-buffered pipeline (stage(t+2) after compute barrier;
// s_waitcnt vmcnt(8) at loop top -- never a full drain in the main loop).
// LDS 64KB -> 2 wg/CU; regs free up to 256 (launch_bounds(256,2)).

typedef _Float16 f16;
typedef __attribute__((ext_vector_type(8))) _Float16 f16x8;
typedef __attribute__((ext_vector_type(4))) _Float16 f16x4;
typedef __attribute__((ext_vector_type(4))) float f32x4;

#define MFMA16(a, b, c) __builtin_amdgcn_mfma_f32_16x16x32_f16((a), (b), (c), 0, 0, 0)

#define BATCH 4
#define SEQ   4096
#define DIM   128
#define NB    64
#define WBAND 32
#define LOG2E 1.44269504088896f
#define DTHR  8.0f
#define TSTR  72

#define TILE  16384   // one K or V tile in fragment order: 16 frags x 64 lanes x 16B
#define CHUNKS 8
#define PART_STRIDE 16896  // 16KB o (f16 [2 qh][8 slot][64 lane][16B]) + 512B (m,l)

__device__ __forceinline__ void gl16(const char* g, char* l) {
  __builtin_amdgcn_global_load_lds(
      (const __attribute__((address_space(1))) void*)g,
      (__attribute__((address_space(3))) void*)l, 16, 0, 0);
}

// ---------------------------------------------------------------------------
// Packs K, V into MFMA fragment order (f16), plus V column sums BS.
// KF frag(ks,jt), lane l: K[s0 + jt*16 + (l&15)][ks*32 + (l>>4)*8 + e]
// VF frag(ks2,nt), lane l: V[s0 + ks2*32 + (e>>2)*16 + ((l>>4)&3)*4 + (e&3)]
//                           [nt*16 + (l&15)]   (pi-permuted contraction rows)
__global__ __launch_bounds__(256) void convert_kernel(
    const float* __restrict__ K, const float* __restrict__ V,
    f16* __restrict__ KF, f16* __restrict__ VF, float* __restrict__ BS) {
  __shared__ f16 T[128 * TSTR];
  const int blk = blockIdx.x;
  const int b = blk >> 6, jb = blk & 63;
  const int s0 = jb * 64;
  const int t = threadIdx.x;

  // V -> T (d-major transpose, f16)
#pragma unroll
  for (int i = 0; i < 8; ++i) {
    int idx = t + i * 256;
    int row = idx >> 5;
    int c4 = (idx & 31) * 4;
    float4 v = *(const float4*)(V + (size_t)(b * SEQ + s0 + row) * DIM + c4);
    T[(c4 + 0) * TSTR + row] = (f16)v.x;
    T[(c4 + 1) * TSTR + row] = (f16)v.y;
    T[(c4 + 2) * TSTR + row] = (f16)v.z;
    T[(c4 + 3) * TSTR + row] = (f16)v.w;
  }

  // KF fragments (no LDS needed)
  char* kt = (char*)KF + (size_t)blk * TILE;
#pragma unroll
  for (int i = 0; i < 4; ++i) {
    int idx = t + i * 256;           // frag*64 + lane
    int frag = idx >> 6, lane = idx & 63;
    int ks = frag >> 2, jt = frag & 3;
    int row = jt * 16 + (lane & 15);
    int d0 = ks * 32 + (lane >> 4) * 8;
    const float* src = K + ((size_t)(b * SEQ + s0 + row)) * DIM + d0;
    float4 a = *(const float4*)src;
    float4 d = *(const float4*)(src + 4);
    f16x8 h = {(f16)a.x, (f16)a.y, (f16)a.z, (f16)a.w,
               (f16)d.x, (f16)d.y, (f16)d.z, (f16)d.w};
    *(f16x8*)(kt + idx * 16) = h;
  }
  __syncthreads();

  // VF fragments with pi row-permutation, gathered from T
  char* vt = (char*)VF + (size_t)blk * TILE;
#pragma unroll
  for (int i = 0; i < 4; ++i) {
    int idx = t + i * 256;
    int frag = idx >> 6, lane = idx & 63;
    int ks2 = frag >> 3, nt = frag & 7;
    int d = nt * 16 + (lane & 15);
    int k0 = ks2 * 32 + ((lane >> 4) & 3) * 4;
    f16x4 x = *(const f16x4*)(T + d * TSTR + k0);
    f16x4 y = *(const f16x4*)(T + d * TSTR + k0 + 16);
    f16x8 h = {x[0], x[1], x[2], x[3], y[0], y[1], y[2], y[3]};
    *(f16x8*)(vt + idx * 16) = h;
  }

  if (t < 128) {
    float s = 0.f;
    for (int k = 0; k < 64; ++k) s += (float)T[t * TSTR + k];
    BS[(b * NB + jb) * DIM + t] = s;
  }
}

// ---------------------------------------------------------------------------
// Pair-wg attention, double-buffered fragment tiles, counted vmcnt.
// LDS: buf{0,1} x (K 16K @ +0, V 16K @ +16384) = 65536 B.
__global__ __launch_bounds__(256, 2) void attn_kernel(
    const float* __restrict__ Q, const f16* __restrict__ KF,
    const f16* __restrict__ VF, char* __restrict__ PART) {
  __shared__ __align__(16) char smem[65536];

  const int id = blockIdx.x;
  const int lin = (id & 7) * 128 + (id >> 3);  // XCD-contiguous pair bands
  const int ck = lin & 7;
  const int pair = lin >> 3;   // 0..127
  const int b = pair >> 5, p = pair & 31;

  const int t = threadIdx.x;
  const int w = t >> 6, l = t & 63, lg = l >> 4, ll = l & 15;
  const int half = w >> 1, qh = w & 1;   // wave -> (block-in-pair, q-half)
  const int myib = p * 2 + half;

  const int jloU = max(0, p * 2 - WBAND);
  const int jhiU = min(NB, p * 2 + 1 + WBAND);
  const int lenU = jhiU - jloU;            // 33..64
  const int c = (lenU + CHUNKS - 1) >> 3;  // 5..8
  const int j0 = jloU + ck * c;
  const int nloc = min(c, jhiU - j0);      // may be <= 0 -> zero partial
  const int mylo = max(0, myib - WBAND);
  const int myhi = min(NB, myib + WBAND);

  // Q fragments (pre-scaled by log2 e), loaded f32 direct from global.
  f16x8 qf[2][4];
#pragma unroll
  for (int s = 0; s < 2; ++s) {
    const float* qrow =
        Q + ((size_t)(b * SEQ + myib * 64 + qh * 32 + s * 16 + ll)) * DIM;
#pragma unroll
    for (int ks = 0; ks < 4; ++ks) {
      int d0 = ks * 32 + lg * 8;
      float4 a = *(const float4*)(qrow + d0);
      float4 cc = *(const float4*)(qrow + d0 + 4);
      float vv[8] = {a.x, a.y, a.z, a.w, cc.x, cc.y, cc.z, cc.w};
#pragma unroll
      for (int e = 0; e < 8; ++e) qf[s][ks][e] = (f16)(vv[e] * LOG2E);
    }
  }
  // All Q loads complete before staging begins (keeps loop vmcnt counts exact).
  asm volatile("s_waitcnt vmcnt(0)" ::: "memory");

  float m2[2] = {0.f, 0.f};   // running max (log2 domain); 0 = masked baseline
  float ell[2] = {0.f, 0.f};  // per-lane partial row sums
  f32x4 o[2][8];
#pragma unroll
  for (int s = 0; s < 2; ++s)
#pragma unroll
    for (int nt = 0; nt < 8; ++nt) o[s][nt] = (f32x4){0.f, 0.f, 0.f, 0.f};

  // stage tile jb into buffer buf (8 gl16 per thread: 4 K + 4 V)
  auto stage = [&](int buf, int jb) {
    const char* kg = (const char*)KF + ((size_t)(b * NB + jb)) * TILE + t * 16;
    const char* vg = (const char*)VF + ((size_t)(b * NB + jb)) * TILE + t * 16;
    char* kl = smem + buf * 32768 + t * 16;
#pragma unroll
    for (int i = 0; i < 4; ++i) gl16(kg + i * 4096, kl + i * 4096);
#pragma unroll
    for (int i = 0; i < 4; ++i) gl16(vg + i * 4096, kl + 16384 + i * 4096);
  };

  if (nloc > 0) {
    stage(0, j0);
    if (nloc > 1) stage(1, j0 + 1);

    for (int tt = 0; tt < nloc; ++tt) {
      // tile tt's 8 loads are the oldest; tt+1's 8 may stay in flight.
      if (tt + 1 < nloc) {
        asm volatile("s_waitcnt vmcnt(8)" ::: "memory");
      } else {
        asm volatile("s_waitcnt vmcnt(0)" ::: "memory");
      }
      __builtin_amdgcn_s_barrier();
      __builtin_amdgcn_sched_barrier(0);

      const int j = j0 + tt;
      const char* kb = smem + (tt & 1) * 32768;
      const char* vb = kb + 16384;

      if (j >= mylo && j < myhi) {  // wave-uniform
        // ---- QK^T (swapped): sacc[s][jt][r] = S[q][k = jt*16 + lg*4 + r]
        f32x4 sacc[2][4];
#pragma unroll
        for (int s = 0; s < 2; ++s)
#pragma unroll
          for (int jt = 0; jt < 4; ++jt) sacc[s][jt] = (f32x4){0.f, 0.f, 0.f, 0.f};

        __builtin_amdgcn_s_setprio(1);
#pragma unroll
        for (int ks = 0; ks < 4; ++ks) {
#pragma unroll
          for (int jt = 0; jt < 4; ++jt) {
            f16x8 kf = *(const f16x8*)(kb + (ks * 4 + jt) * 1024 + l * 16);
            sacc[0][jt] = MFMA16(kf, qf[0][ks], sacc[0][jt]);
            sacc[1][jt] = MFMA16(kf, qf[1][ks], sacc[1][jt]);
          }
        }
        __builtin_amdgcn_s_setprio(0);

        // ---- softmax in-register; pa = lane's own p values (pi-permuted V)
        f16x8 pa[2][2];
#pragma unroll
        for (int s = 0; s < 2; ++s) {
          float vm = sacc[s][0][0];
#pragma unroll
          for (int jt = 0; jt < 4; ++jt)
#pragma unroll
            for (int r = 0; r < 4; ++r) vm = fmaxf(vm, sacc[s][jt][r]);
          vm = fmaxf(vm, __shfl_xor(vm, 16));
          vm = fmaxf(vm, __shfl_xor(vm, 32));

          if (__any(vm - m2[s] > DTHR)) {
            float nm = fmaxf(m2[s], vm);
            float scl = __builtin_amdgcn_exp2f(m2[s] - nm);
            m2[s] = nm;
            ell[s] *= scl;
            float sb[4];
#pragma unroll
            for (int r = 0; r < 4; ++r) sb[r] = __shfl(scl, lg * 4 + r);
#pragma unroll
            for (int nt = 0; nt < 8; ++nt)
#pragma unroll
              for (int r = 0; r < 4; ++r) o[s][nt][r] *= sb[r];
          }

          float rsum = 0.f;
#pragma unroll
          for (int ks2 = 0; ks2 < 2; ++ks2) {
            f16x8 pv;
#pragma unroll
            for (int u = 0; u < 2; ++u) {
#pragma unroll
              for (int r = 0; r < 4; ++r) {
                float pe = __builtin_amdgcn_exp2f(sacc[s][ks2 * 2 + u][r] - m2[s]);
                rsum += pe;
                pv[u * 4 + r] = (f16)pe;
              }
            }
            pa[s][ks2] = pv;
          }
          ell[s] += rsum;
        }

        // ---- PV: B = pi-permuted V fragments from LDS
        __builtin_amdgcn_s_setprio(1);
#pragma unroll
        for (int ks2 = 0; ks2 < 2; ++ks2) {
#pragma unroll
          for (int nt = 0; nt < 8; ++nt) {
            f16x8 vbf = *(const f16x8*)(vb + (ks2 * 8 + nt) * 1024 + l * 16);
            o[0][nt] = MFMA16(pa[0][ks2], vbf, o[0][nt]);
            o[1][nt] = MFMA16(pa[1][ks2], vbf, o[1][nt]);
          }
        }
        __builtin_amdgcn_s_setprio(0);
      }

      __builtin_amdgcn_s_barrier();            // all waves done with buf[tt&1]
      if (tt + 2 < nloc) stage(tt & 1, j0 + tt + 2);
    }
  }

  // finalize per-row sums across lg lanes
#pragma unroll
  for (int s = 0; s < 2; ++s) {
    ell[s] += __shfl_xor(ell[s], 16);
    ell[s] += __shfl_xor(ell[s], 32);
  }

  // partial store, coalesced 16B/lane: [qh][slot=s*4+g][lane][16B]
  char* pb = PART + ((size_t)((pair * CHUNKS + ck) * 2 + half)) * PART_STRIDE;
#pragma unroll
  for (int s = 0; s < 2; ++s)
#pragma unroll
    for (int g = 0; g < 4; ++g) {
      f16x8 hh;
#pragma unroll
      for (int r = 0; r < 4; ++r) {
        hh[r] = (f16)o[s][2 * g][r];
        hh[4 + r] = (f16)o[s][2 * g + 1][r];
      }
      *(f16x8*)(pb + qh * 8192 + ((s * 4 + g) * 64 + l) * 16) = hh;
    }
  if (lg == 0) {
#pragma unroll
    for (int s = 0; s < 2; ++s)
      *(float2*)(pb + 16384 + (qh * 32 + s * 16 + ll) * 8) =
          make_float2(m2[s], ell[s]);
  }
}

// ---------------------------------------------------------------------------
// Flash-merge of 8 chunk partials + closed-form out-of-band correction.
__global__ __launch_bounds__(256) void merge_kernel(
    const char* __restrict__ PART, const float* __restrict__ BS,
    float* __restrict__ Out) {
  __shared__ float VoutS[DIM];
  __shared__ float mlS[CHUNKS][64][2];

  const int id = blockIdx.x;
  const int lin = (id & 7) * 32 + (id >> 3);  // match attn pair->XCD mapping
  const int pair = lin >> 1, half = lin & 1;
  const int b = pair >> 5;
  const int ib = (pair & 31) * 2 + half;
  const int t = threadIdx.x;
  const int l = t & 63, lg = (t >> 4) & 3, ll = t & 15;
  const int sub = (t >> 6) & 1, qh = t >> 7;

  const int jlo = max(0, ib - WBAND);
  const int jhi = min(NB, ib + WBAND);
  const float cnt_out = (float)(SEQ - (jhi - jlo) * 64);

  if (t < DIM) {
    float s = 0.f;
    for (int j = 0; j < jlo; ++j) s += BS[(b * NB + j) * DIM + t];
    for (int j = jhi; j < NB; ++j) s += BS[(b * NB + j) * DIM + t];
    VoutS[t] = s;
  }

  const size_t pb0 = ((size_t)(pair * CHUNKS * 2 + half)) * PART_STRIDE;
  for (int i = t; i < CHUNKS * 64; i += 256) {
    int k = i >> 6, row = i & 63;
    *(float2*)&mlS[k][row][0] = *(const float2*)(
        PART + pb0 + (size_t)k * 2 * PART_STRIDE + 16384 + row * 8);
  }
  __syncthreads();

  float aw[4][CHUNKS], en[4], inv[4];
#pragma unroll
  for (int r = 0; r < 4; ++r) {
    int row = qh * 32 + sub * 16 + lg * 4 + r;
    float M = mlS[0][row][0];
#pragma unroll
    for (int k = 1; k < CHUNKS; ++k) M = fmaxf(M, mlS[k][row][0]);
    en[r] = __builtin_amdgcn_exp2f(-M);
    float den = cnt_out * en[r];
#pragma unroll
    for (int k = 0; k < CHUNKS; ++k) {
      aw[r][k] = __builtin_amdgcn_exp2f(mlS[k][row][0] - M);
      den += aw[r][k] * mlS[k][row][1];
    }
    inv[r] = 1.f / den;
  }

  float acc[8][4];
#pragma unroll
  for (int nt = 0; nt < 8; ++nt)
#pragma unroll
    for (int r = 0; r < 4; ++r) acc[nt][r] = 0.f;

  for (int k = 0; k < CHUNKS; ++k) {
    const char* oc = PART + pb0 + (size_t)k * 2 * PART_STRIDE + qh * 8192;
#pragma unroll
    for (int g = 0; g < 4; ++g) {
      f16x8 h = *(const f16x8*)(oc + ((sub * 4 + g) * 64 + l) * 16);
#pragma unroll
      for (int r = 0; r < 4; ++r) {
        acc[2 * g][r] += aw[r][k] * (float)h[r];
        acc[2 * g + 1][r] += aw[r][k] * (float)h[4 + r];
      }
    }
  }

  const int q0 = ib * 64;
#pragma unroll
  for (int nt = 0; nt < 8; ++nt) {
    int col = nt * 16 + ll;
    float vout = VoutS[col];
#pragma unroll
    for (int r = 0; r < 4; ++r) {
      int row = qh * 32 + sub * 16 + lg * 4 + r;
      Out[((size_t)(b * SEQ + q0 + row)) * DIM + col] =
          (acc[nt][r] + en[r] * vout) * inv[r];
    }
  }
}

// ---------------------------------------------------------------------------
extern "C" void kernel_launch(void* const* d_in, const int* in_sizes, int n_in,
                              void* d_out, int out_size, void* d_ws, size_t ws_size,
                              hipStream_t stream) {
  const float* Q = (const float*)d_in[0];
  const float* K = (const float*)d_in[1];
  const float* V = (const float*)d_in[2];
  float* Out = (float*)d_out;

  char* ws = (char*)d_ws;
  f16* KF = (f16*)ws;                                   // 4 MB
  f16* VF = (f16*)(ws + (size_t)BATCH * NB * TILE);     // 4 MB
  float* BS = (float*)(ws + 2 * (size_t)BATCH * NB * TILE);  // 128 KB
  char* PART = ws + 2 * (size_t)BATCH * NB * TILE + (size_t)BATCH * NB * DIM * 4;

  convert_kernel<<<dim3(BATCH * NB), 256, 0, stream>>>(K, V, KF, VF, BS);
  attn_kernel<<<dim3(BATCH * NB / 2 * CHUNKS), 256, 0, stream>>>(Q, KF, VF, PART);
  merge_kernel<<<dim3(BATCH * NB), 256, 0, stream>>>(PART, BS, Out);
}

// Round 5
// 64.210 us; speedup vs baseline: 1.4089x; 1.0314x over previous
//
#include <hip/hip_runtime.h>

// Banded-block sparse attention, B=4, S=4096, D=128, block=64, w=32.
// Masked scores are 0 (not -inf) -> closed-form out-of-band correction.
// fp16 MFMA path, exp2 domain, swapped QK^T, exact online softmax.
//
// R5: software-pipelined softmax (T15): per iter, QK^T(t) then PV(t-1) then
// softmax(t) in ONE branch-free block -> PV(t-1) MFMAs interleave with
// softmax(t) VALU (independent). V staging lags K by one tile so V(t-1)
// survives until PV(t-1); counted vmcnt(8) completes exactly {K(t),V(t-1)}.
// Rescale is unconditional (register deps on o sequence it after PV).

typedef _Float16 f16;
typedef __attribute__((ext_vector_type(8))) _Float16 f16x8;
typedef __attribute__((ext_vector_type(4))) _Float16 f16x4;
typedef __attribute__((ext_vector_type(4))) float f32x4;

#define MFMA16(a, b, c) __builtin_amdgcn_mfma_f32_16x16x32_f16((a), (b), (c), 0, 0, 0)

#define BATCH 4
#define SEQ   4096
#define DIM   128
#define NB    64
#define WBAND 32
#define LOG2E 1.44269504088896f
#define TSTR  72

#define TILE  16384   // one K or V tile in fragment order: 16 frags x 64 lanes x 16B
#define CHUNKS 8
#define PART_STRIDE 16896  // 16KB o (f16 [2 qh][8 slot][64 lane][16B]) + 512B (m,l)

#define WAIT8 asm volatile("s_waitcnt vmcnt(8)" ::: "memory")
#define WAIT4 asm volatile("s_waitcnt vmcnt(4)" ::: "memory")
#define WAIT0 asm volatile("s_waitcnt vmcnt(0)" ::: "memory")

__device__ __forceinline__ void gl16(const char* g, char* l) {
  __builtin_amdgcn_global_load_lds(
      (const __attribute__((address_space(1))) void*)g,
      (__attribute__((address_space(3))) void*)l, 16, 0, 0);
}

// ---------------------------------------------------------------------------
// Packs K, V into MFMA fragment order (f16), plus V column sums BS.
// KF frag(ks,jt), lane l: K[s0 + jt*16 + (l&15)][ks*32 + (l>>4)*8 + e]
// VF frag(ks2,nt), lane l: V[s0 + ks2*32 + (e>>2)*16 + ((l>>4)&3)*4 + (e&3)]
//                           [nt*16 + (l&15)]   (pi-permuted contraction rows)
__global__ __launch_bounds__(256) void convert_kernel(
    const float* __restrict__ K, const float* __restrict__ V,
    f16* __restrict__ KF, f16* __restrict__ VF, float* __restrict__ BS) {
  __shared__ f16 T[128 * TSTR];
  const int blk = blockIdx.x;
  const int b = blk >> 6, jb = blk & 63;
  const int s0 = jb * 64;
  const int t = threadIdx.x;

  // V -> T (d-major transpose, f16)
#pragma unroll
  for (int i = 0; i < 8; ++i) {
    int idx = t + i * 256;
    int row = idx >> 5;
    int c4 = (idx & 31) * 4;
    float4 v = *(const float4*)(V + (size_t)(b * SEQ + s0 + row) * DIM + c4);
    T[(c4 + 0) * TSTR + row] = (f16)v.x;
    T[(c4 + 1) * TSTR + row] = (f16)v.y;
    T[(c4 + 2) * TSTR + row] = (f16)v.z;
    T[(c4 + 3) * TSTR + row] = (f16)v.w;
  }

  // KF fragments (no LDS needed)
  char* kt = (char*)KF + (size_t)blk * TILE;
#pragma unroll
  for (int i = 0; i < 4; ++i) {
    int idx = t + i * 256;           // frag*64 + lane
    int frag = idx >> 6, lane = idx & 63;
    int ks = frag >> 2, jt = frag & 3;
    int row = jt * 16 + (lane & 15);
    int d0 = ks * 32 + (lane >> 4) * 8;
    const float* src = K + ((size_t)(b * SEQ + s0 + row)) * DIM + d0;
    float4 a = *(const float4*)src;
    float4 d = *(const float4*)(src + 4);
    f16x8 h = {(f16)a.x, (f16)a.y, (f16)a.z, (f16)a.w,
               (f16)d.x, (f16)d.y, (f16)d.z, (f16)d.w};
    *(f16x8*)(kt + idx * 16) = h;
  }
  __syncthreads();

  // VF fragments with pi row-permutation, gathered from T
  char* vt = (char*)VF + (size_t)blk * TILE;
#pragma unroll
  for (int i = 0; i < 4; ++i) {
    int idx = t + i * 256;
    int frag = idx >> 6, lane = idx & 63;
    int ks2 = frag >> 3, nt = frag & 7;
    int d = nt * 16 + (lane & 15);
    int k0 = ks2 * 32 + ((lane >> 4) & 3) * 4;
    f16x4 x = *(const f16x4*)(T + d * TSTR + k0);
    f16x4 y = *(const f16x4*)(T + d * TSTR + k0 + 16);
    f16x8 h = {x[0], x[1], x[2], x[3], y[0], y[1], y[2], y[3]};
    *(f16x8*)(vt + idx * 16) = h;
  }

  if (t < 128) {
    float s = 0.f;
    for (int k = 0; k < 64; ++k) s += (float)T[t * TSTR + k];
    BS[(b * NB + jb) * DIM + t] = s;
  }
}

// ---------------------------------------------------------------------------
// Pair-wg attention; K double-buffered, V double-buffered with 1-tile lag.
// LDS: Kbuf{0,1} @0 (2x16K), Vbuf{0,1} @32768 (2x16K) = 65536 B.
__global__ __launch_bounds__(256, 2) void attn_kernel(
    const float* __restrict__ Q, const f16* __restrict__ KF,
    const f16* __restrict__ VF, char* __restrict__ PART) {
  __shared__ __align__(16) char smem[65536];

  const int id = blockIdx.x;
  const int lin = (id & 7) * 128 + (id >> 3);  // XCD-contiguous pair bands
  const int ck = lin & 7;
  const int pair = lin >> 3;   // 0..127
  const int b = pair >> 5, p = pair & 31;

  const int t = threadIdx.x;
  const int w = t >> 6, l = t & 63, lg = l >> 4, ll = l & 15;
  const int half = w >> 1, qh = w & 1;   // wave -> (block-in-pair, q-half)
  const int myib = p * 2 + half;

  const int jloU = max(0, p * 2 - WBAND);
  const int jhiU = min(NB, p * 2 + 1 + WBAND);
  const int lenU = jhiU - jloU;            // 33..64
  // balanced chunks: ck gets base + (ck<rem) tiles
  const int base = lenU >> 3, rem = lenU & 7;
  const int j0 = jloU + ck * base + min(ck, rem);
  const int nloc = base + (ck < rem ? 1 : 0);   // >= 4 always
  const int mylo = max(0, myib - WBAND);
  const int myhi = min(NB, myib + WBAND);

  // Q fragments (pre-scaled by log2 e), loaded f32 direct from global.
  f16x8 qf[2][4];
#pragma unroll
  for (int s = 0; s < 2; ++s) {
    const float* qrow =
        Q + ((size_t)(b * SEQ + myib * 64 + qh * 32 + s * 16 + ll)) * DIM;
#pragma unroll
    for (int ks = 0; ks < 4; ++ks) {
      int d0 = ks * 32 + lg * 8;
      float4 a = *(const float4*)(qrow + d0);
      float4 cc = *(const float4*)(qrow + d0 + 4);
      float vv[8] = {a.x, a.y, a.z, a.w, cc.x, cc.y, cc.z, cc.w};
#pragma unroll
      for (int e = 0; e < 8; ++e) qf[s][ks][e] = (f16)(vv[e] * LOG2E);
    }
  }
  WAIT0;  // Q loads drained -> staging vmcnt counts are exact

  float m2[2] = {0.f, 0.f};   // running max (log2 domain); 0 = masked baseline
  float ell[2] = {0.f, 0.f};  // per-lane partial row sums
  f32x4 o[2][8];
#pragma unroll
  for (int s = 0; s < 2; ++s)
#pragma unroll
    for (int nt = 0; nt < 8; ++nt) o[s][nt] = (f32x4){0.f, 0.f, 0.f, 0.f};

  auto stageK = [&](int buf, int jb) {
    const char* kg = (const char*)KF + ((size_t)(b * NB + jb)) * TILE + t * 16;
    char* kl = smem + buf * 16384 + t * 16;
#pragma unroll
    for (int i = 0; i < 4; ++i) gl16(kg + i * 4096, kl + i * 4096);
  };
  auto stageV = [&](int buf, int jb) {
    const char* vg = (const char*)VF + ((size_t)(b * NB + jb)) * TILE + t * 16;
    char* vl = smem + 32768 + buf * 16384 + t * 16;
#pragma unroll
    for (int i = 0; i < 4; ++i) gl16(vg + i * 4096, vl + i * 4096);
  };

  f16x8 paA[2][2];   // pa of previous active tile
  bool have = false;

  auto QKT = [&](f32x4 sacc[2][4], const char* kb) {
    __builtin_amdgcn_s_setprio(1);
#pragma unroll
    for (int ks = 0; ks < 4; ++ks) {
#pragma unroll
      for (int jt = 0; jt < 4; ++jt) {
        f16x8 kf = *(const f16x8*)(kb + (ks * 4 + jt) * 1024 + l * 16);
        sacc[0][jt] = MFMA16(kf, qf[0][ks], sacc[0][jt]);
        sacc[1][jt] = MFMA16(kf, qf[1][ks], sacc[1][jt]);
      }
    }
    __builtin_amdgcn_s_setprio(0);
  };
  auto PV = [&](const char* vb) {
    __builtin_amdgcn_s_setprio(1);
#pragma unroll
    for (int ks2 = 0; ks2 < 2; ++ks2) {
#pragma unroll
      for (int nt = 0; nt < 8; ++nt) {
        f16x8 vbf = *(const f16x8*)(vb + (ks2 * 8 + nt) * 1024 + l * 16);
        o[0][nt] = MFMA16(paA[0][ks2], vbf, o[0][nt]);
        o[1][nt] = MFMA16(paA[1][ks2], vbf, o[1][nt]);
      }
    }
    __builtin_amdgcn_s_setprio(0);
  };
  // branch-free online softmax; writes new pa into paA (after PV consumed it:
  // callers sequence PV before SOFTMAX; o-deps order rescale after PV MFMAs)
  auto SOFTMAX = [&](const f32x4 sacc[2][4]) {
#pragma unroll
    for (int s = 0; s < 2; ++s) {
      float vm = fmaxf(fmaxf(sacc[s][0][0], sacc[s][0][1]),
                       fmaxf(sacc[s][0][2], sacc[s][0][3]));
#pragma unroll
      for (int jt = 1; jt < 4; ++jt)
#pragma unroll
        for (int r = 0; r < 4; ++r) vm = fmaxf(vm, sacc[s][jt][r]);
      vm = fmaxf(vm, __shfl_xor(vm, 16));
      vm = fmaxf(vm, __shfl_xor(vm, 32));
      float nm = fmaxf(m2[s], vm);
      float scl = __builtin_amdgcn_exp2f(m2[s] - nm);
      m2[s] = nm;
      float rsum = 0.f;
#pragma unroll
      for (int ks2 = 0; ks2 < 2; ++ks2) {
        f16x8 pv;
#pragma unroll
        for (int u = 0; u < 2; ++u)
#pragma unroll
          for (int r = 0; r < 4; ++r) {
            float pe = __builtin_amdgcn_exp2f(sacc[s][ks2 * 2 + u][r] - nm);
            rsum += pe;
            pv[u * 4 + r] = (f16)pe;
          }
        paA[s][ks2] = pv;
      }
      ell[s] = ell[s] * scl + rsum;
      float sb[4];
#pragma unroll
      for (int r = 0; r < 4; ++r) sb[r] = __shfl(scl, lg * 4 + r);
#pragma unroll
      for (int nt = 0; nt < 8; ++nt)
#pragma unroll
        for (int r = 0; r < 4; ++r) o[s][nt][r] *= sb[r];
    }
  };

  {
    // prologue: batch P1 = {K(0), V(0)} (8), P2 = {K(1)} (4)
    stageK(0, j0);
    stageV(0, j0);
    if (nloc > 1) stageK(1, j0 + 1);

    for (int tt = 0; tt < nloc; ++tt) {
      // top wait: completes exactly {K(tt), V(tt-1)} (see batch accounting)
      if (tt == 0) {
        if (nloc > 1) { WAIT8; } else { WAIT4; }
      } else if (tt + 1 < nloc) {
        WAIT8;
      } else {
        WAIT4;
      }
      __builtin_amdgcn_s_barrier();
      __builtin_amdgcn_sched_barrier(0);

      const int j = j0 + tt;
      const char* kb = smem + (tt & 1) * 16384;
      const char* vb = smem + 32768 + ((tt - 1) & 1) * 16384;
      const bool doQK = (j >= mylo) && (j < myhi);  // wave-uniform

      if (doQK && have) {
        // fused hot path: one straight-line block; PV(t-1) MFMAs interleave
        // with softmax(t) VALU (independent streams).
        f32x4 sacc[2][4];
#pragma unroll
        for (int s = 0; s < 2; ++s)
#pragma unroll
          for (int jt = 0; jt < 4; ++jt) sacc[s][jt] = (f32x4){0.f, 0.f, 0.f, 0.f};
        QKT(sacc, kb);
        PV(vb);
        SOFTMAX(sacc);
      } else if (doQK) {
        f32x4 sacc[2][4];
#pragma unroll
        for (int s = 0; s < 2; ++s)
#pragma unroll
          for (int jt = 0; jt < 4; ++jt) sacc[s][jt] = (f32x4){0.f, 0.f, 0.f, 0.f};
        QKT(sacc, kb);
        SOFTMAX(sacc);
      } else if (have) {
        PV(vb);  // flush pending tile at the end of this wave's active run
      }
      have = doQK;

      __builtin_amdgcn_s_barrier();            // buffers consumed by all waves
      if (tt + 2 < nloc) stageK(tt & 1, j0 + tt + 2);       // K batch first
      if (tt + 1 < nloc) stageV((tt + 1) & 1, j0 + tt + 1); // then V batch
    }

    // epilogue: PV of the last active tile
    WAIT0;
    __builtin_amdgcn_s_barrier();
    if (have) PV(smem + 32768 + ((nloc - 1) & 1) * 16384);
  }

  // finalize per-row sums across lg lanes
#pragma unroll
  for (int s = 0; s < 2; ++s) {
    ell[s] += __shfl_xor(ell[s], 16);
    ell[s] += __shfl_xor(ell[s], 32);
  }

  // partial store, coalesced 16B/lane: [qh][slot=s*4+g][lane][16B]
  char* pb = PART + ((size_t)((pair * CHUNKS + ck) * 2 + half)) * PART_STRIDE;
#pragma unroll
  for (int s = 0; s < 2; ++s)
#pragma unroll
    for (int g = 0; g < 4; ++g) {
      f16x8 hh;
#pragma unroll
      for (int r = 0; r < 4; ++r) {
        hh[r] = (f16)o[s][2 * g][r];
        hh[4 + r] = (f16)o[s][2 * g + 1][r];
      }
      *(f16x8*)(pb + qh * 8192 + ((s * 4 + g) * 64 + l) * 16) = hh;
    }
  if (lg == 0) {
#pragma unroll
    for (int s = 0; s < 2; ++s)
      *(float2*)(pb + 16384 + (qh * 32 + s * 16 + ll) * 8) =
          make_float2(m2[s], ell[s]);
  }
}

// ---------------------------------------------------------------------------
// Flash-merge of 8 chunk partials + closed-form out-of-band correction.
__global__ __launch_bounds__(256) void merge_kernel(
    const char* __restrict__ PART, const float* __restrict__ BS,
    float* __restrict__ Out) {
  __shared__ float VoutS[DIM];
  __shared__ float mlS[CHUNKS][64][2];

  const int id = blockIdx.x;
  const int lin = (id & 7) * 32 + (id >> 3);  // match attn pair->XCD mapping
  const int pair = lin >> 1, half = lin & 1;
  const int b = pair >> 5;
  const int ib = (pair & 31) * 2 + half;
  const int t = threadIdx.x;
  const int l = t & 63, lg = (t >> 4) & 3, ll = t & 15;
  const int sub = (t >> 6) & 1, qh = t >> 7;

  const int jlo = max(0, ib - WBAND);
  const int jhi = min(NB, ib + WBAND);
  const float cnt_out = (float)(SEQ - (jhi - jlo) * 64);

  if (t < DIM) {
    float s = 0.f;
    for (int j = 0; j < jlo; ++j) s += BS[(b * NB + j) * DIM + t];
    for (int j = jhi; j < NB; ++j) s += BS[(b * NB + j) * DIM + t];
    VoutS[t] = s;
  }

  const size_t pb0 = ((size_t)(pair * CHUNKS * 2 + half)) * PART_STRIDE;
  for (int i = t; i < CHUNKS * 64; i += 256) {
    int k = i >> 6, row = i & 63;
    *(float2*)&mlS[k][row][0] = *(const float2*)(
        PART + pb0 + (size_t)k * 2 * PART_STRIDE + 16384 + row * 8);
  }
  __syncthreads();

  float aw[4][CHUNKS], en[4], inv[4];
#pragma unroll
  for (int r = 0; r < 4; ++r) {
    int row = qh * 32 + sub * 16 + lg * 4 + r;
    float M = mlS[0][row][0];
#pragma unroll
    for (int k = 1; k < CHUNKS; ++k) M = fmaxf(M, mlS[k][row][0]);
    en[r] = __builtin_amdgcn_exp2f(-M);
    float den = cnt_out * en[r];
#pragma unroll
    for (int k = 0; k < CHUNKS; ++k) {
      aw[r][k] = __builtin_amdgcn_exp2f(mlS[k][row][0] - M);
      den += aw[r][k] * mlS[k][row][1];
    }
    inv[r] = 1.f / den;
  }

  float acc[8][4];
#pragma unroll
  for (int nt = 0; nt < 8; ++nt)
#pragma unroll
    for (int r = 0; r < 4; ++r) acc[nt][r] = 0.f;

  for (int k = 0; k < CHUNKS; ++k) {
    const char* oc = PART + pb0 + (size_t)k * 2 * PART_STRIDE + qh * 8192;
#pragma unroll
    for (int g = 0; g < 4; ++g) {
      f16x8 h = *(const f16x8*)(oc + ((sub * 4 + g) * 64 + l) * 16);
#pragma unroll
      for (int r = 0; r < 4; ++r) {
        acc[2 * g][r] += aw[r][k] * (float)h[r];
        acc[2 * g + 1][r] += aw[r][k] * (float)h[4 + r];
      }
    }
  }

  const int q0 = ib * 64;
#pragma unroll
  for (int nt = 0; nt < 8; ++nt) {
    int col = nt * 16 + ll;
    float vout = VoutS[col];
#pragma unroll
    for (int r = 0; r < 4; ++r) {
      int row = qh * 32 + sub * 16 + lg * 4 + r;
      Out[((size_t)(b * SEQ + q0 + row)) * DIM + col] =
          (acc[nt][r] + en[r] * vout) * inv[r];
    }
  }
}

// ---------------------------------------------------------------------------
extern "C" void kernel_launch(void* const* d_in, const int* in_sizes, int n_in,
                              void* d_out, int out_size, void* d_ws, size_t ws_size,
                              hipStream_t stream) {
  const float* Q = (const float*)d_in[0];
  const float* K = (const float*)d_in[1];
  const float* V = (const float*)d_in[2];
  float* Out = (float*)d_out;

  char* ws = (char*)d_ws;
  f16* KF = (f16*)ws;                                   // 4 MB
  f16* VF = (f16*)(ws + (size_t)BATCH * NB * TILE);     // 4 MB
  float* BS = (float*)(ws + 2 * (size_t)BATCH * NB * TILE);  // 128 KB
  char* PART = ws + 2 * (size_t)BATCH * NB * TILE + (size_t)BATCH * NB * DIM * 4;

  convert_kernel<<<dim3(BATCH * NB), 256, 0, stream>>>(K, V, KF, VF, BS);
  attn_kernel<<<dim3(BATCH * NB / 2 * CHUNKS), 256, 0, stream>>>(Q, KF, VF, PART);
  merge_kernel<<<dim3(BATCH * NB), 256, 0, stream>>>(PART, BS, Out);
}